// Round 1
// 748.214 us; speedup vs baseline: 1.0038x; 1.0038x over previous
//
#include <hip/hip_runtime.h>

// AdjacencyMatrix: G = softmax(theta @ phi^T) per (n,t), theta/phi = z @ W^T + b
// N=4 T=32 V=1024 C_IN=256 C_OUT=64.  NT=128 row-groups of 1024 rows.
//
// This version swaps MFMA operands (W/phi as A, z/theta as B) so each lane's
// acc quad holds 4 CONSECUTIVE OUTPUT COLUMNS of a single row:
//   D col = lane&15  -> B index (row of z / theta)
//   D row = (lane>>4)*4 + reg -> A index (W channel / phi col)
// => float4 stores, per-lane-scalar softmax state, 2 shuffles instead of 32.

#define LOG2E 1.44269504088896340736f

typedef float  floatx4 __attribute__((ext_vector_type(4)));
typedef short  shortx8 __attribute__((ext_vector_type(8)));

__device__ __forceinline__ unsigned short f2bf(float f) {
  unsigned int u = __builtin_bit_cast(unsigned int, f);
  u += 0x7fffu + ((u >> 16) & 1u);           // RNE
  return (unsigned short)(u >> 16);
}

__device__ __forceinline__ shortx8 load_cvt_bf16x8(const float* p) {
  float4 f0 = *(const float4*)p;
  float4 f1 = *(const float4*)(p + 4);
  shortx8 a;
  a[0] = (short)f2bf(f0.x); a[1] = (short)f2bf(f0.y);
  a[2] = (short)f2bf(f0.z); a[3] = (short)f2bf(f0.w);
  a[4] = (short)f2bf(f1.x); a[5] = (short)f2bf(f1.y);
  a[6] = (short)f2bf(f1.z); a[7] = (short)f2bf(f1.w);
  return a;
}

// ---------------------------------------------------------------------------
// Kernel 1: theta/phi projection. 1024 WGs x 256 thr; WG = 128 rows, 128 cols
// (cols 0..63 theta [pre-scaled by log2e], 64..127 phi). K=256 fully in LDS.
// mfma(W_frag, z_frag, acc): lane holds out-row v=c16, out-cols c=q4*4+r.
// ---------------------------------------------------------------------------
__global__ __launch_bounds__(256, 2)
void k_proj(const float* __restrict__ z,
            const float* __restrict__ tw, const float* __restrict__ tb,
            const float* __restrict__ pw, const float* __restrict__ pb,
            unsigned short* __restrict__ theta, unsigned short* __restrict__ phi)
{
  __shared__ unsigned short Wl[128 * 256];   // bf16 bits, XOR-swizzled k-groups
  const int tid  = threadIdx.x;
  const int lane = tid & 63;
  const int wv   = tid >> 6;
  const int c16  = lane & 15;
  const int q4   = lane >> 4;
  const size_t r0 = (size_t)blockIdx.x * 128;

  // stage concat[theta_w*log2e ; phi_w] -> LDS bf16 (swizzle: group g of row n
  // stored at group g^(n&31); 16B-aligned, conflict-free b128 reads)
  #pragma unroll
  for (int i = 0; i < 16; ++i) {
    int p = tid + i * 256;   // 0..4095 (row, k-group-of-8)
    int n = p >> 5;
    int g = p & 31;
    const float* src = (n < 64) ? (tw + (size_t)n * 256 + g * 8)
                                : (pw + (size_t)(n - 64) * 256 + g * 8);
    float sc = (n < 64) ? LOG2E : 1.0f;
    float4 f0 = *(const float4*)src;
    float4 f1 = *(const float4*)(src + 4);
    union { unsigned short h[8]; int4 v; } u;
    u.h[0] = f2bf(f0.x * sc); u.h[1] = f2bf(f0.y * sc);
    u.h[2] = f2bf(f0.z * sc); u.h[3] = f2bf(f0.w * sc);
    u.h[4] = f2bf(f1.x * sc); u.h[5] = f2bf(f1.y * sc);
    u.h[6] = f2bf(f1.z * sc); u.h[7] = f2bf(f1.w * sc);
    *(int4*)(&Wl[n * 256 + ((g ^ (n & 31)) * 8)]) = u.v;
  }
  __syncthreads();

  floatx4 acc[2][8];
  #pragma unroll
  for (int rt = 0; rt < 2; ++rt)
    #pragma unroll
    for (int ct = 0; ct < 8; ++ct) acc[rt][ct] = 0.0f;

  // wave rows: r0 + wv*32 + {rt*16 + c16}; z as B operand (same load as A)
  const float* z0 = z + (r0 + (size_t)wv * 32 + c16) * 256 + q4 * 8;
  #pragma unroll
  for (int s = 0; s < 8; ++s) {
    shortx8 a0 = load_cvt_bf16x8(z0 + s * 32);
    shortx8 a1 = load_cvt_bf16x8(z0 + 16 * 256 + s * 32);
    #pragma unroll
    for (int ct = 0; ct < 8; ++ct) {
      int n = ct * 16 + c16;
      int g = s * 4 + q4;
      shortx8 b = *(const shortx8*)(&Wl[n * 256 + ((g ^ (n & 31)) * 8)]);
      // swapped: W is A, z is B -> D rows = W channels, D cols = z rows
      acc[0][ct] = __builtin_amdgcn_mfma_f32_16x16x32_bf16(b, a0, acc[0][ct], 0, 0, 0);
      acc[1][ct] = __builtin_amdgcn_mfma_f32_16x16x32_bf16(b, a1, acc[1][ct], 0, 0, 0);
    }
  }

  // epilogue: lane holds row v = r0+wv*32+rt*16+c16, cols c0..c0+3 where
  // c0 = ct*16 + q4*4. Pack 4 bf16 -> 8B store. theta bias pre-scaled log2e.
  #pragma unroll
  for (int ct = 0; ct < 8; ++ct) {
    int c0 = ct * 16 + q4 * 4;
    const bool is_t = (c0 < 64);
    const float* bp = is_t ? (tb + c0) : (pb + (c0 - 64));
    float4 bias = *(const float4*)bp;
    float sc = is_t ? LOG2E : 1.0f;
    #pragma unroll
    for (int rt = 0; rt < 2; ++rt) {
      size_t gr = r0 + (size_t)wv * 32 + rt * 16 + c16;
      union { unsigned short h[4]; uint2 v; } u;
      u.h[0] = f2bf(acc[rt][ct][0] + bias.x * sc);
      u.h[1] = f2bf(acc[rt][ct][1] + bias.y * sc);
      u.h[2] = f2bf(acc[rt][ct][2] + bias.z * sc);
      u.h[3] = f2bf(acc[rt][ct][3] + bias.w * sc);
      unsigned short* dst = is_t ? theta : phi;
      *(uint2*)(dst + gr * 64 + (c0 & 63)) = u.v;
    }
  }
}

// ---------------------------------------------------------------------------
// Kernel 2: S = theta.phi^T + row softmax + write G.
// 8192 WGs (nt 0..127 x 64 16-row blocks), 256 thr = 4 waves.
// Wave wv: 16 rows x cols [wv*256, wv*256+256): 16 col-tiles, K=64 in 2 steps.
// acc[16] = 64 VGPR -> 3 waves/SIMD. mfma(phi, theta, acc): lane holds ONE
// row v = vb*16+c16 and cols ct*16 + q4*4 + {0..3} -> float4 stores, scalar
// per-lane softmax state. theta pre-scaled by log2e -> exp2.
// ---------------------------------------------------------------------------
__global__ __launch_bounds__(256, 3)
void k_adj(const unsigned short* __restrict__ theta,
           const unsigned short* __restrict__ phi,
           float* __restrict__ out)
{
  __shared__ __align__(16) float redm[16][4];
  __shared__ __align__(16) float reds[16][4];
  const int tid  = threadIdx.x;
  const int lane = tid & 63;
  const int wv   = tid >> 6;
  const int c16  = lane & 15;
  const int q4   = lane >> 4;
  const int nt   = blockIdx.x >> 6;
  const int vb   = blockIdx.x & 63;

  const unsigned short* tbase =
      theta + ((size_t)nt * 1024 + vb * 16 + c16) * 64 + q4 * 8;
  const unsigned short* pbase =
      phi + ((size_t)nt * 1024 + wv * 256 + c16) * 64 + q4 * 8;

  floatx4 acc[16];
  #pragma unroll
  for (int ct = 0; ct < 16; ++ct) acc[ct] = 0.0f;

  #pragma unroll
  for (int s = 0; s < 2; ++s) {
    shortx8 t = *(const shortx8*)(tbase + s * 32);
    #pragma unroll
    for (int ct = 0; ct < 16; ++ct) {
      shortx8 p = *(const shortx8*)(pbase + (size_t)ct * 16 * 64 + s * 32);
      // swapped: phi is A (rows = w), theta is B (cols = v)
      acc[ct] = __builtin_amdgcn_mfma_f32_16x16x32_bf16(p, t, acc[ct], 0, 0, 0);
    }
  }

  // ---- softmax over 1024 cols. Lane owns row v=c16 with 64 w-values; the
  // other 3 lanes sharing this row are q4-neighbors -> shfl_xor 16,32 only.
  float m = acc[0][0];
  #pragma unroll
  for (int ct = 0; ct < 16; ++ct)
    #pragma unroll
    for (int r = 0; r < 4; ++r) m = fmaxf(m, acc[ct][r]);
  m = fmaxf(m, __shfl_xor(m, 16, 64));
  m = fmaxf(m, __shfl_xor(m, 32, 64));
  if (lane < 16) redm[c16][wv] = m;
  __syncthreads();

  float4 mv = *(const float4*)(&redm[c16][0]);
  float gmax = fmaxf(fmaxf(mv.x, mv.y), fmaxf(mv.z, mv.w));

  // exp2 with the GLOBAL max (theta pre-scaled by log2e)
  float sum = 0.0f;
  #pragma unroll
  for (int ct = 0; ct < 16; ++ct)
    #pragma unroll
    for (int r = 0; r < 4; ++r) {
      float e = exp2f(acc[ct][r] - gmax);
      acc[ct][r] = e;
      sum += e;
    }
  sum += __shfl_xor(sum, 16, 64);
  sum += __shfl_xor(sum, 32, 64);
  if (lane < 16) reds[c16][wv] = sum;
  __syncthreads();

  float4 sv = *(const float4*)(&reds[c16][0]);
  float rinv = __builtin_amdgcn_rcpf(sv.x + sv.y + sv.z + sv.w);

  // lane writes float4 at (row v, col wv*256 + ct*16 + q4*4); nontemporal to
  // keep the 512 MiB stream from evicting phi/theta in L2.
  float* ob = out + (size_t)nt * 1024 * 1024
                  + (size_t)(vb * 16 + c16) * 1024 + wv * 256 + q4 * 4;
  #pragma unroll
  for (int ct = 0; ct < 16; ++ct) {
    floatx4 g = acc[ct] * rinv;
    __builtin_nontemporal_store(g, (floatx4*)(ob + ct * 16));
  }
}

// ---------------------------------------------------------------------------
extern "C" void kernel_launch(void* const* d_in, const int* in_sizes, int n_in,
                              void* d_out, int out_size, void* d_ws, size_t ws_size,
                              hipStream_t stream) {
  const float* z  = (const float*)d_in[0];
  const float* tw = (const float*)d_in[1];
  const float* tb = (const float*)d_in[2];
  const float* pw = (const float*)d_in[3];
  const float* pb = (const float*)d_in[4];
  float* out = (float*)d_out;

  unsigned short* theta = (unsigned short*)d_ws;                    // 16 MiB
  unsigned short* phi   = theta + (size_t)131072 * 64;              // +16 MiB

  k_proj<<<dim3(1024), dim3(256), 0, stream>>>(z, tw, tb, pw, pb, theta, phi);
  k_adj<<<dim3(8192), dim3(256), 0, stream>>>(theta, phi, out);
}

// Round 3
// 743.509 us; speedup vs baseline: 1.0101x; 1.0063x over previous
//
#include <hip/hip_runtime.h>

// AdjacencyMatrix: G = softmax(theta @ phi^T) per (n,t), theta/phi = z @ W^T + b
// N=4 T=32 V=1024 C_IN=256 C_OUT=64.  NT=128 row-groups of 1024 rows.
//
// MFMA operands swapped (W/phi as A, z/theta as B): lane's acc quad holds 4
// CONSECUTIVE OUTPUT COLUMNS of one row -> float4 stores, scalar softmax state.
// Round 3 = round 2 resubmit (infra failure, kernel never ran): k_adj at
// 8 waves/WG (512 thr), acc[8]=32 VGPR, bounds (512,4) -> 16 waves/CU.

#define LOG2E 1.44269504088896340736f

typedef float  floatx4 __attribute__((ext_vector_type(4)));
typedef short  shortx8 __attribute__((ext_vector_type(8)));

__device__ __forceinline__ unsigned short f2bf(float f) {
  unsigned int u = __builtin_bit_cast(unsigned int, f);
  u += 0x7fffu + ((u >> 16) & 1u);           // RNE
  return (unsigned short)(u >> 16);
}

__device__ __forceinline__ shortx8 load_cvt_bf16x8(const float* p) {
  float4 f0 = *(const float4*)p;
  float4 f1 = *(const float4*)(p + 4);
  shortx8 a;
  a[0] = (short)f2bf(f0.x); a[1] = (short)f2bf(f0.y);
  a[2] = (short)f2bf(f0.z); a[3] = (short)f2bf(f0.w);
  a[4] = (short)f2bf(f1.x); a[5] = (short)f2bf(f1.y);
  a[6] = (short)f2bf(f1.z); a[7] = (short)f2bf(f1.w);
  return a;
}

// ---------------------------------------------------------------------------
// Kernel 1: theta/phi projection. 1024 WGs x 256 thr; WG = 128 rows, 128 cols
// (cols 0..63 theta [pre-scaled by log2e], 64..127 phi). K=256 fully in LDS.
// mfma(W_frag, z_frag, acc): lane holds out-row v=c16, out-cols c=q4*4+r.
// ---------------------------------------------------------------------------
__global__ __launch_bounds__(256, 2)
void k_proj(const float* __restrict__ z,
            const float* __restrict__ tw, const float* __restrict__ tb,
            const float* __restrict__ pw, const float* __restrict__ pb,
            unsigned short* __restrict__ theta, unsigned short* __restrict__ phi)
{
  __shared__ unsigned short Wl[128 * 256];   // bf16 bits, XOR-swizzled k-groups
  const int tid  = threadIdx.x;
  const int lane = tid & 63;
  const int wv   = tid >> 6;
  const int c16  = lane & 15;
  const int q4   = lane >> 4;
  const size_t r0 = (size_t)blockIdx.x * 128;

  // stage concat[theta_w*log2e ; phi_w] -> LDS bf16 (swizzle: group g of row n
  // stored at group g^(n&31); 16B-aligned, conflict-free b128 reads)
  #pragma unroll
  for (int i = 0; i < 16; ++i) {
    int p = tid + i * 256;   // 0..4095 (row, k-group-of-8)
    int n = p >> 5;
    int g = p & 31;
    const float* src = (n < 64) ? (tw + (size_t)n * 256 + g * 8)
                                : (pw + (size_t)(n - 64) * 256 + g * 8);
    float sc = (n < 64) ? LOG2E : 1.0f;
    float4 f0 = *(const float4*)src;
    float4 f1 = *(const float4*)(src + 4);
    union { unsigned short h[8]; int4 v; } u;
    u.h[0] = f2bf(f0.x * sc); u.h[1] = f2bf(f0.y * sc);
    u.h[2] = f2bf(f0.z * sc); u.h[3] = f2bf(f0.w * sc);
    u.h[4] = f2bf(f1.x * sc); u.h[5] = f2bf(f1.y * sc);
    u.h[6] = f2bf(f1.z * sc); u.h[7] = f2bf(f1.w * sc);
    *(int4*)(&Wl[n * 256 + ((g ^ (n & 31)) * 8)]) = u.v;
  }
  __syncthreads();

  floatx4 acc[2][8];
  #pragma unroll
  for (int rt = 0; rt < 2; ++rt)
    #pragma unroll
    for (int ct = 0; ct < 8; ++ct) acc[rt][ct] = 0.0f;

  // wave rows: r0 + wv*32 + {rt*16 + c16}; z as B operand (same load as A)
  const float* z0 = z + (r0 + (size_t)wv * 32 + c16) * 256 + q4 * 8;
  #pragma unroll
  for (int s = 0; s < 8; ++s) {
    shortx8 a0 = load_cvt_bf16x8(z0 + s * 32);
    shortx8 a1 = load_cvt_bf16x8(z0 + 16 * 256 + s * 32);
    #pragma unroll
    for (int ct = 0; ct < 8; ++ct) {
      int n = ct * 16 + c16;
      int g = s * 4 + q4;
      shortx8 b = *(const shortx8*)(&Wl[n * 256 + ((g ^ (n & 31)) * 8)]);
      // swapped: W is A, z is B -> D rows = W channels, D cols = z rows
      acc[0][ct] = __builtin_amdgcn_mfma_f32_16x16x32_bf16(b, a0, acc[0][ct], 0, 0, 0);
      acc[1][ct] = __builtin_amdgcn_mfma_f32_16x16x32_bf16(b, a1, acc[1][ct], 0, 0, 0);
    }
  }

  // epilogue: lane holds row v = r0+wv*32+rt*16+c16, cols c0..c0+3 where
  // c0 = ct*16 + q4*4. Pack 4 bf16 -> 8B store. theta bias pre-scaled log2e.
  #pragma unroll
  for (int ct = 0; ct < 8; ++ct) {
    int c0 = ct * 16 + q4 * 4;
    const bool is_t = (c0 < 64);
    const float* bp = is_t ? (tb + c0) : (pb + (c0 - 64));
    float4 bias = *(const float4*)bp;
    float sc = is_t ? LOG2E : 1.0f;
    #pragma unroll
    for (int rt = 0; rt < 2; ++rt) {
      size_t gr = r0 + (size_t)wv * 32 + rt * 16 + c16;
      union { unsigned short h[4]; uint2 v; } u;
      u.h[0] = f2bf(acc[rt][ct][0] + bias.x * sc);
      u.h[1] = f2bf(acc[rt][ct][1] + bias.y * sc);
      u.h[2] = f2bf(acc[rt][ct][2] + bias.z * sc);
      u.h[3] = f2bf(acc[rt][ct][3] + bias.w * sc);
      unsigned short* dst = is_t ? theta : phi;
      *(uint2*)(dst + gr * 64 + (c0 & 63)) = u.v;
    }
  }
}

// ---------------------------------------------------------------------------
// Kernel 2: S = theta.phi^T + row softmax + write G.
// 8192 WGs (nt 0..127 x 64 16-row blocks), 512 thr = 8 waves.
// Wave wv: 16 rows x cols [wv*128, wv*128+128): 8 col-tiles, K=64 in 2 steps.
// acc[8] = 32 VGPR -> bounds (512,4) = 16 waves/CU; all 8 phi frags per
// K-step hoistable within the 128-VGPR cap (latency hiding).
// mfma(phi, theta, acc): lane holds ONE row v = vb*16+c16, cols
// wv*128 + ct*16 + q4*4 + {0..3} -> float4 stores, scalar softmax state.
// theta pre-scaled by log2e -> exp2.
// ---------------------------------------------------------------------------
__global__ __launch_bounds__(512, 4)
void k_adj(const unsigned short* __restrict__ theta,
           const unsigned short* __restrict__ phi,
           float* __restrict__ out)
{
  __shared__ __align__(16) float redm[16][8];
  __shared__ __align__(16) float reds[16][8];
  const int tid  = threadIdx.x;
  const int lane = tid & 63;
  const int wv   = tid >> 6;          // 0..7
  const int c16  = lane & 15;
  const int q4   = lane >> 4;
  const int nt   = blockIdx.x >> 6;
  const int vb   = blockIdx.x & 63;

  const unsigned short* tbase =
      theta + ((size_t)nt * 1024 + vb * 16 + c16) * 64 + q4 * 8;
  const unsigned short* pbase =
      phi + ((size_t)nt * 1024 + wv * 128 + c16) * 64 + q4 * 8;

  floatx4 acc[8];
  #pragma unroll
  for (int ct = 0; ct < 8; ++ct) acc[ct] = 0.0f;

  #pragma unroll
  for (int s = 0; s < 2; ++s) {
    shortx8 t = *(const shortx8*)(tbase + s * 32);
    #pragma unroll
    for (int ct = 0; ct < 8; ++ct) {
      shortx8 p = *(const shortx8*)(pbase + (size_t)ct * 16 * 64 + s * 32);
      // swapped: phi is A (rows = w), theta is B (cols = v)
      acc[ct] = __builtin_amdgcn_mfma_f32_16x16x32_bf16(p, t, acc[ct], 0, 0, 0);
    }
  }

  // ---- softmax over 1024 cols. Lane owns row v=c16 with 32 w-values; the
  // other 3 lanes sharing this row in-wave are q4-neighbors -> shfl 16,32;
  // cross-wave combine over 8 waves via LDS.
  float m = acc[0][0];
  #pragma unroll
  for (int ct = 0; ct < 8; ++ct)
    #pragma unroll
    for (int r = 0; r < 4; ++r) m = fmaxf(m, acc[ct][r]);
  m = fmaxf(m, __shfl_xor(m, 16, 64));
  m = fmaxf(m, __shfl_xor(m, 32, 64));
  if (lane < 16) redm[c16][wv] = m;
  __syncthreads();

  float4 mv0 = *(const float4*)(&redm[c16][0]);
  float4 mv1 = *(const float4*)(&redm[c16][4]);
  float gmax = fmaxf(fmaxf(fmaxf(mv0.x, mv0.y), fmaxf(mv0.z, mv0.w)),
                     fmaxf(fmaxf(mv1.x, mv1.y), fmaxf(mv1.z, mv1.w)));

  // exp2 with the GLOBAL max (theta pre-scaled by log2e)
  float sum = 0.0f;
  #pragma unroll
  for (int ct = 0; ct < 8; ++ct)
    #pragma unroll
    for (int r = 0; r < 4; ++r) {
      float e = exp2f(acc[ct][r] - gmax);
      acc[ct][r] = e;
      sum += e;
    }
  sum += __shfl_xor(sum, 16, 64);
  sum += __shfl_xor(sum, 32, 64);
  if (lane < 16) reds[c16][wv] = sum;
  __syncthreads();

  float4 sv0 = *(const float4*)(&reds[c16][0]);
  float4 sv1 = *(const float4*)(&reds[c16][4]);
  float rinv = __builtin_amdgcn_rcpf((sv0.x + sv0.y + sv0.z + sv0.w) +
                                     (sv1.x + sv1.y + sv1.z + sv1.w));

  // lane writes float4 at (row v, col wv*128 + ct*16 + q4*4); nontemporal to
  // keep the 512 MiB stream from evicting phi/theta in L2.
  float* ob = out + (size_t)nt * 1024 * 1024
                  + (size_t)(vb * 16 + c16) * 1024 + wv * 128 + q4 * 4;
  #pragma unroll
  for (int ct = 0; ct < 8; ++ct) {
    floatx4 g = acc[ct] * rinv;
    __builtin_nontemporal_store(g, (floatx4*)(ob + ct * 16));
  }
}

// ---------------------------------------------------------------------------
extern "C" void kernel_launch(void* const* d_in, const int* in_sizes, int n_in,
                              void* d_out, int out_size, void* d_ws, size_t ws_size,
                              hipStream_t stream) {
  const float* z  = (const float*)d_in[0];
  const float* tw = (const float*)d_in[1];
  const float* tb = (const float*)d_in[2];
  const float* pw = (const float*)d_in[3];
  const float* pb = (const float*)d_in[4];
  float* out = (float*)d_out;

  unsigned short* theta = (unsigned short*)d_ws;                    // 16 MiB
  unsigned short* phi   = theta + (size_t)131072 * 64;              // +16 MiB

  k_proj<<<dim3(1024), dim3(256), 0, stream>>>(z, tw, tb, pw, pb, theta, phi);
  k_adj<<<dim3(8192), dim3(512), 0, stream>>>(theta, phi, out);
}